// Round 1
// baseline (1392.848 us; speedup 1.0000x reference)
//
#include <hip/hip_runtime.h>
#include <cstdint>

// GIN: N=50000 nodes, D=128 feat, E=800000 edges, L=3 layers.
// per layer: agg = x + scatter_add(x[src] -> dst); h = relu(agg@W1+b1); x = relu(h@W2+b2)

constexpr int N = 50000;
constexpr int D = 128;
constexpr int E = 800000;
constexpr int L = 3;

// ---------------- copy: agg = x ----------------
__global__ __launch_bounds__(256) void k_copy(const float4* __restrict__ in,
                                              float4* __restrict__ out, int n4) {
  int i = blockIdx.x * 256 + threadIdx.x;
  if (i < n4) out[i] = in[i];
}

// ---------------- scatter: agg[dst] += x[src] ----------------
// one thread per (edge, dim) element. Handles edge_index stored as int32 OR
// int64 (detected on device: for int64, the high words of values < 2^31 are 0).
__global__ __launch_bounds__(256) void k_scatter(const float* __restrict__ x,
                                                 const int* __restrict__ ei32,
                                                 float* __restrict__ agg) {
  long long i = (long long)blockIdx.x * 256 + threadIdx.x;
  int e = (int)(i >> 7);   // edge id
  int d = (int)(i & 127);  // feature dim
  if (e >= E) return;
  // int64 detection: indices are < 50000, so as-int64 every odd 32-bit word is 0.
  bool is64 = (ei32[1] == 0) && (ei32[3] == 0) && (ei32[5] == 0);
  int s, t;
  if (is64) {
    s = ei32[2 * (size_t)e];
    t = ei32[2 * ((size_t)E + e)];
  } else {
    s = ei32[e];
    t = ei32[(size_t)E + e];
  }
  atomicAdd(agg + (size_t)t * D + d, x[(size_t)s * D + d]);
}

// ---------------- fused GEMM + bias + ReLU ----------------
// C[N,128] = relu(A[N,128] @ W[128,128] + b). W staged in LDS (64 KB).
// 16 rows per block, 256 threads, 8 output cols per thread.
__global__ __launch_bounds__(256) void k_gemm_bias_relu(const float* __restrict__ A,
                                                        const float* __restrict__ W,
                                                        const float* __restrict__ bias,
                                                        float* __restrict__ C) {
  __shared__ float Ws[D * D];
  {
    const float4* W4 = (const float4*)W;
    float4* Ws4 = (float4*)Ws;
#pragma unroll
    for (int i = 0; i < (D * D / 4) / 256; ++i)  // 16 iters
      Ws4[i * 256 + threadIdx.x] = W4[i * 256 + threadIdx.x];
  }
  __syncthreads();

  int r = blockIdx.x * 16 + (threadIdx.x >> 4);
  int c0 = (threadIdx.x & 15) << 3;
  const float* Arow = A + (size_t)r * D;

  float acc[8];
#pragma unroll
  for (int j = 0; j < 8; ++j) acc[j] = bias[c0 + j];

  for (int k0 = 0; k0 < D; k0 += 4) {
    float4 av = *(const float4*)(Arow + k0);
    float a4[4] = {av.x, av.y, av.z, av.w};
#pragma unroll
    for (int kk = 0; kk < 4; ++kk) {
#pragma unroll
      for (int j = 0; j < 8; ++j)
        acc[j] = fmaf(a4[kk], Ws[(k0 + kk) * D + c0 + j], acc[j]);
    }
  }

  float* Crow = C + (size_t)r * D + c0;
#pragma unroll
  for (int j = 0; j < 8; ++j) Crow[j] = fmaxf(acc[j], 0.0f);
}

extern "C" void kernel_launch(void* const* d_in, const int* in_sizes, int n_in,
                              void* d_out, int out_size, void* d_ws, size_t ws_size,
                              hipStream_t stream) {
  const float* x0 = (const float*)d_in[0];
  const int* ei   = (const int*)d_in[1];
  const float* W1 = (const float*)d_in[2];
  const float* b1 = (const float*)d_in[3];
  const float* W2 = (const float*)d_in[4];
  const float* b2 = (const float*)d_in[5];
  float* out = (float*)d_out;

  float* agg = (float*)d_ws;                    // N*D floats
  float* h   = agg + (size_t)N * D;             // N*D floats

  const int n4 = N * D / 4;
  const dim3 blk(256);
  const long long sc_items = (long long)E * D;
  const int sc_blocks = (int)((sc_items + 255) / 256);

  for (int l = 0; l < L; ++l) {
    const float* xc = (l == 0) ? x0 : out;
    // agg = x
    k_copy<<<(n4 + 255) / 256, blk, 0, stream>>>((const float4*)xc, (float4*)agg, n4);
    // agg[dst] += x[src]
    k_scatter<<<sc_blocks, blk, 0, stream>>>(xc, ei, agg);
    // h = relu(agg @ W1[l] + b1[l])
    k_gemm_bias_relu<<<N / 16, blk, 0, stream>>>(agg, W1 + (size_t)l * D * D,
                                                 b1 + (size_t)l * D, h);
    // x' = relu(h @ W2[l] + b2[l])   (written into d_out, read next layer)
    k_gemm_bias_relu<<<N / 16, blk, 0, stream>>>(h, W2 + (size_t)l * D * D,
                                                 b2 + (size_t)l * D, out);
  }
}

// Round 2
// 493.229 us; speedup vs baseline: 2.8239x; 2.8239x over previous
//
#include <hip/hip_runtime.h>
#include <cstdint>

// GIN: N=50000 nodes, D=128 feat, E=800000 edges, L=3 layers.
// per layer: agg = x + gather-sum over CSR(dst); h = relu(agg@W1+b1); x = relu(h@W2+b2)
// CSR built once per launch (edge_index reused across all 3 layers).

constexpr int N = 50000;
constexpr int D = 128;
constexpr int E = 800000;
constexpr int L = 3;
constexpr int NB_SCAN = (N + 255) / 256;  // 196

// ---- edge index load (handles int32 or int64 storage) ----
// int64 detection: indices < 50000, so as-int64 every odd 32-bit word is 0.
__device__ __forceinline__ bool ei_is64(const int* ei) {
  return (ei[1] == 0) && (ei[3] == 0) && (ei[5] == 0);
}
__device__ __forceinline__ int ei_src(const int* ei, int e, bool is64) {
  return is64 ? ei[2 * (size_t)e] : ei[e];
}
__device__ __forceinline__ int ei_dst(const int* ei, int e, bool is64) {
  return is64 ? ei[2 * ((size_t)E + e)] : ei[(size_t)E + e];
}

// ---------------- CSR build ----------------
__global__ __launch_bounds__(256) void k_hist(const int* __restrict__ ei,
                                              int* __restrict__ cnt) {
  int e = blockIdx.x * 256 + threadIdx.x;
  if (e >= E) return;
  bool is64 = ei_is64(ei);
  atomicAdd(cnt + ei_dst(ei, e, is64), 1);
}

// block-wise exclusive scan of cnt -> off (per-block), block totals -> bsum
__global__ __launch_bounds__(256) void k_scan1(const int* __restrict__ cnt,
                                               int* __restrict__ off,
                                               int* __restrict__ bsum) {
  __shared__ int s[256];
  int i = blockIdx.x * 256 + threadIdx.x;
  int v = (i < N) ? cnt[i] : 0;
  s[threadIdx.x] = v;
  __syncthreads();
#pragma unroll
  for (int o = 1; o < 256; o <<= 1) {
    int t = (threadIdx.x >= o) ? s[threadIdx.x - o] : 0;
    __syncthreads();
    s[threadIdx.x] += t;
    __syncthreads();
  }
  if (i < N) off[i] = s[threadIdx.x] - v;          // exclusive within block
  if (threadIdx.x == 255) bsum[blockIdx.x] = s[255];  // block total
}

// single-block exclusive scan of bsum (NB_SCAN <= 256)
__global__ __launch_bounds__(256) void k_scan2(int* __restrict__ bsum) {
  __shared__ int s[256];
  int v = (threadIdx.x < NB_SCAN) ? bsum[threadIdx.x] : 0;
  s[threadIdx.x] = v;
  __syncthreads();
#pragma unroll
  for (int o = 1; o < 256; o <<= 1) {
    int t = (threadIdx.x >= o) ? s[threadIdx.x - o] : 0;
    __syncthreads();
    s[threadIdx.x] += t;
    __syncthreads();
  }
  if (threadIdx.x < NB_SCAN) bsum[threadIdx.x] = s[threadIdx.x] - v;
}

// finalize offsets, init bump cursors, set off[N] = E
__global__ __launch_bounds__(256) void k_scan3(int* __restrict__ off,
                                               const int* __restrict__ bsum,
                                               int* __restrict__ pos) {
  int i = blockIdx.x * 256 + threadIdx.x;
  if (i < N) {
    int o = off[i] + bsum[i >> 8];
    off[i] = o;
    pos[i] = o;
  }
  if (i == 0) off[N] = E;
}

__global__ __launch_bounds__(256) void k_bucket(const int* __restrict__ ei,
                                                int* __restrict__ pos,
                                                int* __restrict__ sorted_src) {
  int e = blockIdx.x * 256 + threadIdx.x;
  if (e >= E) return;
  bool is64 = ei_is64(ei);
  int s = ei_src(ei, e, is64);
  int t = ei_dst(ei, e, is64);
  int p = atomicAdd(pos + t, 1);
  sorted_src[p] = s;
}

// ---------------- gather-aggregate: agg[n] = x[n] + sum_{j in bucket(n)} x[src_j]
// 256 threads = 8 nodes x 32 lanes; each lane owns 4 contiguous dims (float4).
__global__ __launch_bounds__(256) void k_gather(const float* __restrict__ x,
                                                const int* __restrict__ off,
                                                const int* __restrict__ sorted_src,
                                                float* __restrict__ agg) {
  int n = blockIdx.x * 8 + (threadIdx.x >> 5);
  int d4 = (threadIdx.x & 31) << 2;
  const float4* xr = (const float4*)(x + (size_t)n * D + d4);
  float4 acc = *xr;
  int beg = off[n], end = off[n + 1];
  for (int j = beg; j < end; ++j) {
    int s = sorted_src[j];
    float4 v = *(const float4*)(x + (size_t)s * D + d4);
    acc.x += v.x; acc.y += v.y; acc.z += v.z; acc.w += v.w;
  }
  *(float4*)(agg + (size_t)n * D + d4) = acc;
}

// ---------------- fused GEMM + bias + ReLU ----------------
// C[N,128] = relu(A[N,128] @ W[128,128] + b). W staged in LDS (64 KB).
// 64 rows/block, 256 threads: thread = 4 rows x 8 cols (32 acc).
__global__ __launch_bounds__(256) void k_gemm_bias_relu(const float* __restrict__ A,
                                                        const float* __restrict__ W,
                                                        const float* __restrict__ bias,
                                                        float* __restrict__ C) {
  __shared__ float Ws[D * D];
  {
    const float4* W4 = (const float4*)W;
    float4* Ws4 = (float4*)Ws;
#pragma unroll
    for (int i = 0; i < (D * D / 4) / 256; ++i)  // 16 iters
      Ws4[i * 256 + threadIdx.x] = W4[i * 256 + threadIdx.x];
  }
  __syncthreads();

  const int tr = threadIdx.x >> 4;          // 0..15
  const int c0 = (threadIdx.x & 15) << 3;   // 0..120
  const int r0 = blockIdx.x * 64 + tr * 4;

  int r[4];
#pragma unroll
  for (int i = 0; i < 4; ++i) r[i] = min(r0 + i, N - 1);  // clamp loads

  float acc[4][8];
  float bv[8];
#pragma unroll
  for (int j = 0; j < 8; ++j) bv[j] = bias[c0 + j];
#pragma unroll
  for (int i = 0; i < 4; ++i)
#pragma unroll
    for (int j = 0; j < 8; ++j) acc[i][j] = bv[j];

  for (int k0 = 0; k0 < D; k0 += 4) {
    float4 a[4];
#pragma unroll
    for (int i = 0; i < 4; ++i)
      a[i] = *(const float4*)(A + (size_t)r[i] * D + k0);
#pragma unroll
    for (int kk = 0; kk < 4; ++kk) {
      float4 w0 = *(const float4*)&Ws[(k0 + kk) * D + c0];
      float4 w1 = *(const float4*)&Ws[(k0 + kk) * D + c0 + 4];
      float wv[8] = {w0.x, w0.y, w0.z, w0.w, w1.x, w1.y, w1.z, w1.w};
      float av[4] = {kk == 0 ? a[0].x : kk == 1 ? a[0].y : kk == 2 ? a[0].z : a[0].w,
                     kk == 0 ? a[1].x : kk == 1 ? a[1].y : kk == 2 ? a[1].z : a[1].w,
                     kk == 0 ? a[2].x : kk == 1 ? a[2].y : kk == 2 ? a[2].z : a[2].w,
                     kk == 0 ? a[3].x : kk == 1 ? a[3].y : kk == 2 ? a[3].z : a[3].w};
#pragma unroll
      for (int i = 0; i < 4; ++i)
#pragma unroll
        for (int j = 0; j < 8; ++j)
          acc[i][j] = fmaf(av[i], wv[j], acc[i][j]);
    }
  }

#pragma unroll
  for (int i = 0; i < 4; ++i) {
    int rr = r0 + i;
    if (rr < N) {
      float* Crow = C + (size_t)rr * D + c0;
#pragma unroll
      for (int j = 0; j < 8; ++j) Crow[j] = fmaxf(acc[i][j], 0.0f);
    }
  }
}

extern "C" void kernel_launch(void* const* d_in, const int* in_sizes, int n_in,
                              void* d_out, int out_size, void* d_ws, size_t ws_size,
                              hipStream_t stream) {
  const float* x0 = (const float*)d_in[0];
  const int* ei   = (const int*)d_in[1];
  const float* W1 = (const float*)d_in[2];
  const float* b1 = (const float*)d_in[3];
  const float* W2 = (const float*)d_in[4];
  const float* b2 = (const float*)d_in[5];
  float* out = (float*)d_out;

  // workspace layout
  float* agg = (float*)d_ws;                       // N*D f32
  float* h   = agg + (size_t)N * D;                // N*D f32
  int* off   = (int*)(h + (size_t)N * D);          // N+1
  int* pos   = off + (N + 1);                      // N
  int* bsum  = pos + N;                            // 256
  int* ssrc  = bsum + 256;                         // E

  const dim3 blk(256);

  // ---- CSR build (once; reused across layers) ----
  hipMemsetAsync(pos, 0, (size_t)N * sizeof(int), stream);
  k_hist<<<(E + 255) / 256, blk, 0, stream>>>(ei, pos);
  k_scan1<<<NB_SCAN, blk, 0, stream>>>(pos, off, bsum);
  k_scan2<<<1, blk, 0, stream>>>(bsum);
  k_scan3<<<NB_SCAN, blk, 0, stream>>>(off, bsum, pos);
  k_bucket<<<(E + 255) / 256, blk, 0, stream>>>(ei, pos, ssrc);

  const int gemm_blocks = (N + 63) / 64;  // 782

  for (int l = 0; l < L; ++l) {
    const float* xc = (l == 0) ? x0 : out;
    k_gather<<<N / 8, blk, 0, stream>>>(xc, off, ssrc, agg);
    k_gemm_bias_relu<<<gemm_blocks, blk, 0, stream>>>(agg, W1 + (size_t)l * D * D,
                                                      b1 + (size_t)l * D, h);
    k_gemm_bias_relu<<<gemm_blocks, blk, 0, stream>>>(h, W2 + (size_t)l * D * D,
                                                      b2 + (size_t)l * D, out);
  }
}

// Round 3
// 290.415 us; speedup vs baseline: 4.7961x; 1.6984x over previous
//
#include <hip/hip_runtime.h>
#include <cstdint>

// GIN: N=50000, D=128, E=800000, L=3.
// per layer: agg = x + gather-sum over CSR(dst); h = relu(agg@W1+b1); x = relu(h@W2+b2)
// CSR built once per launch. All feature math in f16 (fp32 accumulate), MFMA GEMMs.

constexpr int N = 50000;
constexpr int D = 128;
constexpr int E = 800000;
constexpr int L = 3;
constexpr int NB_SCAN = (N + 255) / 256;  // 196

typedef _Float16 f16;
typedef _Float16 f16x8 __attribute__((ext_vector_type(8)));
typedef float f32x4 __attribute__((ext_vector_type(4)));

// ---- edge index load (handles int32 or int64 storage) ----
__device__ __forceinline__ bool ei_is64(const int* ei) {
  return (ei[1] == 0) && (ei[3] == 0) && (ei[5] == 0);
}
__device__ __forceinline__ int ei_src(const int* ei, int e, bool is64) {
  return is64 ? ei[2 * (size_t)e] : ei[e];
}
__device__ __forceinline__ int ei_dst(const int* ei, int e, bool is64) {
  return is64 ? ei[2 * ((size_t)E + e)] : ei[(size_t)E + e];
}

// ---------------- CSR build ----------------
__global__ __launch_bounds__(256) void k_hist(const int* __restrict__ ei,
                                              int* __restrict__ cnt) {
  int e = blockIdx.x * 256 + threadIdx.x;
  if (e >= E) return;
  bool is64 = ei_is64(ei);
  atomicAdd(cnt + ei_dst(ei, e, is64), 1);
}

__global__ __launch_bounds__(256) void k_scan1(const int* __restrict__ cnt,
                                               int* __restrict__ off,
                                               int* __restrict__ bsum) {
  __shared__ int s[256];
  int i = blockIdx.x * 256 + threadIdx.x;
  int v = (i < N) ? cnt[i] : 0;
  s[threadIdx.x] = v;
  __syncthreads();
#pragma unroll
  for (int o = 1; o < 256; o <<= 1) {
    int t = (threadIdx.x >= o) ? s[threadIdx.x - o] : 0;
    __syncthreads();
    s[threadIdx.x] += t;
    __syncthreads();
  }
  if (i < N) off[i] = s[threadIdx.x] - v;
  if (threadIdx.x == 255) bsum[blockIdx.x] = s[255];
}

__global__ __launch_bounds__(256) void k_scan2(int* __restrict__ bsum) {
  __shared__ int s[256];
  int v = (threadIdx.x < NB_SCAN) ? bsum[threadIdx.x] : 0;
  s[threadIdx.x] = v;
  __syncthreads();
#pragma unroll
  for (int o = 1; o < 256; o <<= 1) {
    int t = (threadIdx.x >= o) ? s[threadIdx.x - o] : 0;
    __syncthreads();
    s[threadIdx.x] += t;
    __syncthreads();
  }
  if (threadIdx.x < NB_SCAN) bsum[threadIdx.x] = s[threadIdx.x] - v;
}

__global__ __launch_bounds__(256) void k_scan3(int* __restrict__ off,
                                               const int* __restrict__ bsum,
                                               int* __restrict__ pos) {
  int i = blockIdx.x * 256 + threadIdx.x;
  if (i < N) {
    int o = off[i] + bsum[i >> 8];
    off[i] = o;
    pos[i] = o;
  }
  if (i == 0) off[N] = E;
}

__global__ __launch_bounds__(256) void k_bucket(const int* __restrict__ ei,
                                                int* __restrict__ pos,
                                                int* __restrict__ sorted_src) {
  int e = blockIdx.x * 256 + threadIdx.x;
  if (e >= E) return;
  bool is64 = ei_is64(ei);
  int s = ei_src(ei, e, is64);
  int t = ei_dst(ei, e, is64);
  int p = atomicAdd(pos + t, 1);
  sorted_src[p] = s;
}

// ---------------- conversions ----------------
// f32 -> f16, n multiple of 8
__global__ __launch_bounds__(256) void k_cvt(const float* __restrict__ in,
                                             f16* __restrict__ out) {
  int i = blockIdx.x * 256 + threadIdx.x;  // one per 8 elems, grid sized exactly
  float4 v0 = *(const float4*)(in + (size_t)i * 8);
  float4 v1 = *(const float4*)(in + (size_t)i * 8 + 4);
  f16x8 o = {(f16)v0.x, (f16)v0.y, (f16)v0.z, (f16)v0.w,
             (f16)v1.x, (f16)v1.y, (f16)v1.z, (f16)v1.w};
  *(f16x8*)(out + (size_t)i * 8) = o;
}

// weights: Wt[m][c][k] = Wsrc[m][k][c] as f16, m in [0,2L): first L from W1, rest W2
__global__ __launch_bounds__(256) void k_wprep(const float* __restrict__ W1,
                                               const float* __restrict__ W2,
                                               f16* __restrict__ Wt) {
  int i = blockIdx.x * 256 + threadIdx.x;  // 2*L*D*D = 98304, grid exact
  int m = i >> 14;
  int c = (i >> 7) & 127;
  int k = i & 127;
  const float* src = (m < L) ? (W1 + (size_t)m * D * D)
                             : (W2 + (size_t)(m - L) * D * D);
  Wt[i] = (f16)src[(size_t)k * D + c];
}

// ---------------- gather-aggregate (f16): agg[n] = x[n] + sum_{j} x[src_j]
// 256 threads = 16 nodes x 16 lanes; each lane owns 8 contiguous dims (16B).
__global__ __launch_bounds__(256) void k_gather_f16(const f16* __restrict__ x,
                                                    const int* __restrict__ off,
                                                    const int* __restrict__ ssrc,
                                                    f16* __restrict__ agg) {
  int n = blockIdx.x * 16 + (threadIdx.x >> 4);
  int d0 = (threadIdx.x & 15) << 3;
  f16x8 v = *(const f16x8*)(x + (size_t)n * D + d0);
  float acc[8];
#pragma unroll
  for (int j = 0; j < 8; ++j) acc[j] = (float)v[j];
  int beg = off[n], end = off[n + 1];
  for (int p = beg; p < end; ++p) {
    int s = ssrc[p];
    f16x8 u = *(const f16x8*)(x + (size_t)s * D + d0);
#pragma unroll
    for (int j = 0; j < 8; ++j) acc[j] += (float)u[j];
  }
  f16x8 o;
#pragma unroll
  for (int j = 0; j < 8; ++j) o[j] = (f16)acc[j];
  *(f16x8*)(agg + (size_t)n * D + d0) = o;
}

// ---------------- MFMA GEMM + bias + ReLU ----------------
// C[N,128] = relu(A[N,128] @ W[128,128] + b), A f16 row-major, Wt f16 [col][k].
// Block: 256 thr = 4 waves, 64 rows (16 per wave). mfma_f32_16x16x32_f16.
// Writes Ch (f16) always; Cf (fp32) if non-null.
__global__ __launch_bounds__(256) void k_gemm_f16(const f16* __restrict__ A,
                                                  const f16* __restrict__ Wt,
                                                  const float* __restrict__ bias,
                                                  f16* __restrict__ Ch,
                                                  float* __restrict__ Cf) {
  __shared__ f16 Ws[128 * 136];  // Wt staged, rows padded 128->136 (2-way banks = free)
  {
    const f16x8* gsrc = (const f16x8*)Wt;
    for (int i = threadIdx.x; i < 2048; i += 256) {  // 2048 chunks of 8 f16
      int c = i >> 4;
      int k8 = (i & 15) << 3;
      *(f16x8*)&Ws[c * 136 + k8] = gsrc[i];
    }
  }
  __syncthreads();

  const int w = threadIdx.x >> 6;   // wave 0..3
  const int l = threadIdx.x & 63;
  const int l15 = l & 15;
  const int g = l >> 4;             // 0..3
  const int r0 = blockIdx.x * 64 + w * 16;

  // A-frags: lane holds row (l&15), k = t*32 + g*8 + [0..8)
  const int arow = min(r0 + l15, N - 1);
  const f16* Arow = A + (size_t)arow * D;
  f16x8 a[4];
#pragma unroll
  for (int t = 0; t < 4; ++t)
    a[t] = *(const f16x8*)(Arow + t * 32 + g * 8);

  float bcol[8];
#pragma unroll
  for (int c = 0; c < 8; ++c) bcol[c] = bias[c * 16 + l15];

  f32x4 acc[8];
#pragma unroll
  for (int c = 0; c < 8; ++c) acc[c] = (f32x4){0.f, 0.f, 0.f, 0.f};

#pragma unroll
  for (int t = 0; t < 4; ++t) {
#pragma unroll
    for (int c = 0; c < 8; ++c) {
      // B-frag: col = c*16 + l15, k = t*32 + g*8 + [0..8)
      f16x8 b = *(const f16x8*)&Ws[(c * 16 + l15) * 136 + t * 32 + g * 8];
      acc[c] = __builtin_amdgcn_mfma_f32_16x16x32_f16(a[t], b, acc[c], 0, 0, 0);
    }
  }

  // D: col = c*16 + l15, row = r0 + g*4 + r
#pragma unroll
  for (int r = 0; r < 4; ++r) {
    int rr = r0 + g * 4 + r;
    if (rr < N) {
#pragma unroll
      for (int c = 0; c < 8; ++c) {
        int col = c * 16 + l15;
        float vv = fmaxf(acc[c][r] + bcol[c], 0.0f);
        Ch[(size_t)rr * D + col] = (f16)vv;
        if (Cf) Cf[(size_t)rr * D + col] = vv;
      }
    }
  }
}

extern "C" void kernel_launch(void* const* d_in, const int* in_sizes, int n_in,
                              void* d_out, int out_size, void* d_ws, size_t ws_size,
                              hipStream_t stream) {
  const float* x0 = (const float*)d_in[0];
  const int* ei   = (const int*)d_in[1];
  const float* W1 = (const float*)d_in[2];
  const float* b1 = (const float*)d_in[3];
  const float* W2 = (const float*)d_in[4];
  const float* b2 = (const float*)d_in[5];
  float* out = (float*)d_out;

  // workspace layout (f16 arrays first, then ints)
  f16* xh   = (f16*)d_ws;                    // N*D
  f16* aggh = xh + (size_t)N * D;            // N*D
  f16* hh   = aggh + (size_t)N * D;          // N*D
  f16* Wt   = hh + (size_t)N * D;            // 2*L*D*D
  int* off  = (int*)(Wt + (size_t)2 * L * D * D);  // N+1
  int* pos  = off + (N + 1);                 // N
  int* bsum = pos + N;                       // 256
  int* ssrc = bsum + 256;                    // E

  const dim3 blk(256);

  // ---- one-time prep ----
  k_wprep<<<(2 * L * D * D) / 256, blk, 0, stream>>>(W1, W2, Wt);
  k_cvt<<<(N * D / 8 + 255) / 256, blk, 0, stream>>>(x0, xh);

  hipMemsetAsync(pos, 0, (size_t)N * sizeof(int), stream);
  k_hist<<<(E + 255) / 256, blk, 0, stream>>>(ei, pos);
  k_scan1<<<NB_SCAN, blk, 0, stream>>>(pos, off, bsum);
  k_scan2<<<1, blk, 0, stream>>>(bsum);
  k_scan3<<<NB_SCAN, blk, 0, stream>>>(off, bsum, pos);
  k_bucket<<<(E + 255) / 256, blk, 0, stream>>>(ei, pos, ssrc);

  const int gemm_blocks = (N + 63) / 64;  // 782
  const int gather_blocks = N / 16;       // 3125

  for (int l = 0; l < L; ++l) {
    k_gather_f16<<<gather_blocks, blk, 0, stream>>>(xh, off, ssrc, aggh);
    k_gemm_f16<<<gemm_blocks, blk, 0, stream>>>(aggh, Wt + (size_t)l * D * D,
                                                b1 + (size_t)l * D, hh, nullptr);
    k_gemm_f16<<<gemm_blocks, blk, 0, stream>>>(hh, Wt + (size_t)(L + l) * D * D,
                                                b2 + (size_t)l * D, xh,
                                                (l == L - 1) ? out : nullptr);
  }
}